// Round 1
// baseline (97.909 us; speedup 1.0000x reference)
//
#include <hip/hip_runtime.h>
#include <math.h>

// GatingNetwork: logits = x @ W^T + b; softmax; top-2; outputs:
//   [0] weights [N,2], [1] indices [N,2] (as float), [2] mask [N,64], [3] probs [N,64]
// All fp32 compute (no fp32 MFMA on CDNA4; bf16 would flip top-2 ties).

constexpr int D   = 2048;   // d_model
constexpr int E   = 64;     // experts
constexpr int N   = 16384;  // tokens
constexpr int BT  = 64;     // tokens per block
constexpr int BK  = 32;     // k-chunk
constexpr int STRIDE = 68;  // padded LDS stride (k-major tiles); 68*4B keeps 16B alignment
constexpr int LST = 65;     // logits LDS stride (conflict-free column scan)

__global__ __launch_bounds__(256) void gating_kernel(
    const float* __restrict__ x, const float* __restrict__ W,
    const float* __restrict__ bias, float* __restrict__ out)
{
    __shared__ __align__(16) float smem[2 * BK * STRIDE];   // 17408 B
    float (*xs)[STRIDE] = reinterpret_cast<float (*)[STRIDE]>(smem);            // xs[k][token]
    float (*ws)[STRIDE] = reinterpret_cast<float (*)[STRIDE]>(smem + BK*STRIDE);// ws[k][expert]
    float (*lg)[LST]    = reinterpret_cast<float (*)[LST]>(smem);               // reuse: logits[t][e]
    __shared__ float s_max[BT], s_rinv[BT];
    __shared__ int   s_i1[BT], s_i2[BT];

    const int tid = threadIdx.x;
    const int tx = tid & 15;        // expert group: experts 4*tx..4*tx+3
    const int ty = tid >> 4;        // token group:  tokens 4*ty..4*ty+3
    const int tokBase = blockIdx.x * BT;

    // staging task decomposition: 8 k-quads x 64 rows; thread does rows row0 and row0+32
    const int kq   = tid & 7;       // k-quad (4 floats)
    const int row0 = tid >> 3;      // 0..31

    const float* xptr0 = x + (size_t)(tokBase + row0)      * D + kq * 4;
    const float* xptr1 = x + (size_t)(tokBase + row0 + 32) * D + kq * 4;
    const float* wptr0 = W + (size_t)row0        * D + kq * 4;
    const float* wptr1 = W + (size_t)(row0 + 32) * D + kq * 4;

    // prefetch chunk 0 into registers
    float4 px0 = *reinterpret_cast<const float4*>(xptr0);
    float4 px1 = *reinterpret_cast<const float4*>(xptr1);
    float4 pw0 = *reinterpret_cast<const float4*>(wptr0);
    float4 pw1 = *reinterpret_cast<const float4*>(wptr1);

    float acc[4][4] = {};

    for (int kb = 0; kb < D; kb += BK) {
        // write previously-prefetched chunk to LDS (transposed, k-major)
        xs[kq*4+0][row0]    = px0.x; xs[kq*4+1][row0]    = px0.y;
        xs[kq*4+2][row0]    = px0.z; xs[kq*4+3][row0]    = px0.w;
        xs[kq*4+0][row0+32] = px1.x; xs[kq*4+1][row0+32] = px1.y;
        xs[kq*4+2][row0+32] = px1.z; xs[kq*4+3][row0+32] = px1.w;
        ws[kq*4+0][row0]    = pw0.x; ws[kq*4+1][row0]    = pw0.y;
        ws[kq*4+2][row0]    = pw0.z; ws[kq*4+3][row0]    = pw0.w;
        ws[kq*4+0][row0+32] = pw1.x; ws[kq*4+1][row0+32] = pw1.y;
        ws[kq*4+2][row0+32] = pw1.z; ws[kq*4+3][row0+32] = pw1.w;
        __syncthreads();

        // issue next chunk's global loads (land during compute below)
        if (kb + BK < D) {
            const int o = kb + BK;
            px0 = *reinterpret_cast<const float4*>(xptr0 + o);
            px1 = *reinterpret_cast<const float4*>(xptr1 + o);
            pw0 = *reinterpret_cast<const float4*>(wptr0 + o);
            pw1 = *reinterpret_cast<const float4*>(wptr1 + o);
        }

        #pragma unroll
        for (int k = 0; k < BK; ++k) {
            const float4 xf = *reinterpret_cast<const float4*>(&xs[k][ty*4]);
            const float4 wf = *reinterpret_cast<const float4*>(&ws[k][tx*4]);
            const float xr[4] = {xf.x, xf.y, xf.z, xf.w};
            const float wr[4] = {wf.x, wf.y, wf.z, wf.w};
            #pragma unroll
            for (int i = 0; i < 4; ++i)
                #pragma unroll
                for (int j = 0; j < 4; ++j)
                    acc[i][j] = fmaf(xr[i], wr[j], acc[i][j]);
        }
        __syncthreads();
    }

    // ---- epilogue ----
    float bj[4];
    #pragma unroll
    for (int j = 0; j < 4; ++j) bj[j] = bias[tx*4 + j];

    #pragma unroll
    for (int i = 0; i < 4; ++i)
        #pragma unroll
        for (int j = 0; j < 4; ++j)
            lg[ty*4 + i][tx*4 + j] = acc[i][j] + bj[j];
    __syncthreads();

    float* outWt = out;
    float* outIx = out + (size_t)N * 2;
    float* outMk = out + (size_t)N * 4;
    float* outPr = out + (size_t)N * 4 + (size_t)N * E;

    if (tid < BT) {
        const int t = tid;
        float m1 = -3.4e38f, m2 = -3.4e38f;
        int i1 = 0, i2 = 0;
        for (int e = 0; e < E; ++e) {
            const float l = lg[t][e];
            if (l > m1)      { m2 = m1; i2 = i1; m1 = l; i1 = e; }
            else if (l > m2) { m2 = l;  i2 = e; }
        }
        float s = 0.f;
        for (int e = 0; e < E; ++e) s += expf(lg[t][e] - m1);
        const float e2 = expf(m2 - m1);
        const float inv12 = 1.f / (1.f + e2);
        const size_t g = (size_t)(tokBase + t);
        outWt[g*2 + 0] = inv12;        // p1/(p1+p2)
        outWt[g*2 + 1] = e2 * inv12;   // p2/(p1+p2)
        outIx[g*2 + 0] = (float)i1;
        outIx[g*2 + 1] = (float)i2;
        s_max[t]  = m1;
        s_rinv[t] = 1.f / s;
        s_i1[t]   = i1;
        s_i2[t]   = i2;
    }
    __syncthreads();

    // coalesced probs + mask write: per wave, one token row of 64 floats
    for (int f = tid; f < BT * E; f += 256) {
        const int t = f >> 6;
        const int e = f & 63;
        const float p = expf(lg[t][e] - s_max[t]) * s_rinv[t];
        const size_t g = (size_t)(tokBase + t) * E + e;
        outPr[g] = p;
        outMk[g] = (e == s_i1[t] || e == s_i2[t]) ? 1.0f : 0.0f;
    }
}

extern "C" void kernel_launch(void* const* d_in, const int* in_sizes, int n_in,
                              void* d_out, int out_size, void* d_ws, size_t ws_size,
                              hipStream_t stream) {
    const float* x = (const float*)d_in[0];
    const float* W = (const float*)d_in[1];
    const float* b = (const float*)d_in[2];
    float* out = (float*)d_out;
    gating_kernel<<<dim3(N / BT), dim3(256), 0, stream>>>(x, W, b, out);
}

// Round 2
// 82.289 us; speedup vs baseline: 1.1898x; 1.1898x over previous
//
#include <hip/hip_runtime.h>
#include <math.h>

// GatingNetwork: logits = x @ W^T + b; softmax; top-2.
// Outputs (fp32, concat): [0] weights [N,2], [1] indices [N,2] (as float),
//                         [2] mask [N,64], [3] probs [N,64]
// Strategy: K-split GEMM (S=2 or 4) for occupancy (round-1 showed 1 wave/SIMD,
// VALUBusy 26%). Partial logits: slice0->probs region, slice1->mask region,
// slices 2,3 -> d_ws (if ws_size >= 8MB). Epilogue sums + softmax + top2.

constexpr int D   = 2048;
constexpr int E   = 64;
constexpr int N   = 16384;
constexpr int BT  = 64;     // tokens per block
constexpr int BK  = 32;     // k-chunk
constexpr int STRIDE = 68;  // padded k-major LDS stride (keeps 16B alignment)

__global__ __launch_bounds__(256) void gemm_partial(
    const float* __restrict__ x, const float* __restrict__ W,
    float* __restrict__ p0, float* __restrict__ p1,
    float* __restrict__ p2, float* __restrict__ p3, int split)
{
    __shared__ __align__(16) float smem[2 * BK * STRIDE];   // 17408 B
    float (*xs)[STRIDE] = reinterpret_cast<float (*)[STRIDE]>(smem);            // xs[k][token]
    float (*wsl)[STRIDE] = reinterpret_cast<float (*)[STRIDE]>(smem + BK*STRIDE);// wsl[k][expert]

    const int tid = threadIdx.x;
    const int tx = tid & 15;        // experts 4*tx..4*tx+3
    const int ty = tid >> 4;        // tokens  4*ty..4*ty+3
    const int s = blockIdx.x >> 8;              // k-slice id
    const int tokBase = (blockIdx.x & 255) * BT;
    const int kLen = D / split;
    const int kStart = s * kLen;

    const int kq   = tid & 7;       // k-quad (4 floats)
    const int row0 = tid >> 3;      // 0..31

    const float* xptr0 = x + (size_t)(tokBase + row0)      * D + kStart + kq * 4;
    const float* xptr1 = x + (size_t)(tokBase + row0 + 32) * D + kStart + kq * 4;
    const float* wptr0 = W + (size_t)row0        * D + kStart + kq * 4;
    const float* wptr1 = W + (size_t)(row0 + 32) * D + kStart + kq * 4;

    float4 px0 = *reinterpret_cast<const float4*>(xptr0);
    float4 px1 = *reinterpret_cast<const float4*>(xptr1);
    float4 pw0 = *reinterpret_cast<const float4*>(wptr0);
    float4 pw1 = *reinterpret_cast<const float4*>(wptr1);

    float acc[4][4] = {};

    for (int kb = 0; kb < kLen; kb += BK) {
        xs[kq*4+0][row0]    = px0.x; xs[kq*4+1][row0]    = px0.y;
        xs[kq*4+2][row0]    = px0.z; xs[kq*4+3][row0]    = px0.w;
        xs[kq*4+0][row0+32] = px1.x; xs[kq*4+1][row0+32] = px1.y;
        xs[kq*4+2][row0+32] = px1.z; xs[kq*4+3][row0+32] = px1.w;
        wsl[kq*4+0][row0]    = pw0.x; wsl[kq*4+1][row0]    = pw0.y;
        wsl[kq*4+2][row0]    = pw0.z; wsl[kq*4+3][row0]    = pw0.w;
        wsl[kq*4+0][row0+32] = pw1.x; wsl[kq*4+1][row0+32] = pw1.y;
        wsl[kq*4+2][row0+32] = pw1.z; wsl[kq*4+3][row0+32] = pw1.w;
        __syncthreads();

        if (kb + BK < kLen) {
            const int o = kb + BK;
            px0 = *reinterpret_cast<const float4*>(xptr0 + o);
            px1 = *reinterpret_cast<const float4*>(xptr1 + o);
            pw0 = *reinterpret_cast<const float4*>(wptr0 + o);
            pw1 = *reinterpret_cast<const float4*>(wptr1 + o);
        }

        #pragma unroll
        for (int k = 0; k < BK; ++k) {
            const float4 xf = *reinterpret_cast<const float4*>(&xs[k][ty*4]);
            const float4 wf = *reinterpret_cast<const float4*>(&wsl[k][tx*4]);
            const float xr[4] = {xf.x, xf.y, xf.z, xf.w};
            const float wr[4] = {wf.x, wf.y, wf.z, wf.w};
            #pragma unroll
            for (int i = 0; i < 4; ++i)
                #pragma unroll
                for (int j = 0; j < 4; ++j)
                    acc[i][j] = fmaf(xr[i], wr[j], acc[i][j]);
        }
        __syncthreads();
    }

    float* dst = (s == 0) ? p0 : (s == 1) ? p1 : (s == 2) ? p2 : p3;
    #pragma unroll
    for (int i = 0; i < 4; ++i) {
        float4 v;
        v.x = acc[i][0]; v.y = acc[i][1]; v.z = acc[i][2]; v.w = acc[i][3];
        *reinterpret_cast<float4*>(dst + (size_t)(tokBase + ty*4 + i) * E + tx*4) = v;
    }
}

__global__ __launch_bounds__(256) void epilogue_kernel(
    const float* __restrict__ p0, const float* __restrict__ p1,
    const float* __restrict__ p2, const float* __restrict__ p3,
    const float* __restrict__ bias, float* __restrict__ out, int split)
{
    __shared__ float lg[BT][E + 1];
    __shared__ float s_max[BT], s_rinv[BT];
    __shared__ int   s_i1[BT], s_i2[BT];

    const int tid = threadIdx.x;
    const int tokBase = blockIdx.x * BT;

    // sum partials + bias into LDS (reads finish before any in-place overwrite)
    for (int f4 = tid; f4 < BT * E / 4; f4 += 256) {
        const size_t g = (size_t)tokBase * E + f4 * 4;
        float4 a = *reinterpret_cast<const float4*>(p0 + g);
        float4 b = *reinterpret_cast<const float4*>(p1 + g);
        float4 v;
        v.x = a.x + b.x; v.y = a.y + b.y; v.z = a.z + b.z; v.w = a.w + b.w;
        if (split == 4) {
            float4 c = *reinterpret_cast<const float4*>(p2 + g);
            float4 d = *reinterpret_cast<const float4*>(p3 + g);
            v.x += c.x + d.x; v.y += c.y + d.y; v.z += c.z + d.z; v.w += c.w + d.w;
        }
        const int t = (f4 * 4) >> 6;
        const int e = (f4 * 4) & 63;
        const float4 bb = *reinterpret_cast<const float4*>(bias + e);
        lg[t][e + 0] = v.x + bb.x;
        lg[t][e + 1] = v.y + bb.y;
        lg[t][e + 2] = v.z + bb.z;
        lg[t][e + 3] = v.w + bb.w;
    }
    __syncthreads();

    float* outWt = out;
    float* outIx = out + (size_t)N * 2;
    float* outMk = out + (size_t)N * 4;
    float* outPr = out + (size_t)N * 4 + (size_t)N * E;

    if (tid < BT) {
        const int t = tid;
        float m1 = -3.4e38f, m2 = -3.4e38f;
        int i1 = 0, i2 = 0;
        for (int e = 0; e < E; ++e) {
            const float l = lg[t][e];
            if (l > m1)      { m2 = m1; i2 = i1; m1 = l; i1 = e; }
            else if (l > m2) { m2 = l;  i2 = e; }
        }
        float ssum = 0.f;
        for (int e = 0; e < E; ++e) ssum += expf(lg[t][e] - m1);
        const float e2 = expf(m2 - m1);
        const float inv12 = 1.f / (1.f + e2);
        const size_t g = (size_t)(tokBase + t);
        outWt[g*2 + 0] = inv12;
        outWt[g*2 + 1] = e2 * inv12;
        outIx[g*2 + 0] = (float)i1;
        outIx[g*2 + 1] = (float)i2;
        s_max[t]  = m1;
        s_rinv[t] = 1.f / ssum;
        s_i1[t]   = i1;
        s_i2[t]   = i2;
    }
    __syncthreads();

    for (int f = tid; f < BT * E; f += 256) {
        const int t = f >> 6;
        const int e = f & 63;
        const float p = expf(lg[t][e] - s_max[t]) * s_rinv[t];
        const size_t g = (size_t)(tokBase + t) * E + e;
        outPr[g] = p;
        outMk[g] = (e == s_i1[t] || e == s_i2[t]) ? 1.0f : 0.0f;
    }
}

extern "C" void kernel_launch(void* const* d_in, const int* in_sizes, int n_in,
                              void* d_out, int out_size, void* d_ws, size_t ws_size,
                              hipStream_t stream) {
    const float* x = (const float*)d_in[0];
    const float* W = (const float*)d_in[1];
    const float* b = (const float*)d_in[2];
    float* out = (float*)d_out;

    float* outMk = out + (size_t)N * 4;
    float* outPr = out + (size_t)N * 4 + (size_t)N * E;

    // slice 0 -> probs region, slice 1 -> mask region; slices 2,3 -> ws if room
    int split = 2;
    float* p0 = outPr;
    float* p1 = outMk;
    float* p2 = outPr;   // unused when split==2
    float* p3 = outMk;
    if (ws_size >= (size_t)2 * N * E * sizeof(float)) {
        split = 4;
        p2 = (float*)d_ws;
        p3 = (float*)d_ws + (size_t)N * E;
    }

    gemm_partial<<<dim3(256 * split), dim3(256), 0, stream>>>(x, W, p0, p1, p2, p3, split);
    epilogue_kernel<<<dim3(N / BT), dim3(256), 0, stream>>>(p0, p1, p2, p3, b, out, split);
}

// Round 3
// 62.181 us; speedup vs baseline: 1.5746x; 1.3234x over previous
//
#include <hip/hip_runtime.h>
#include <math.h>

// GatingNetwork via bf16x3 split-MFMA emulated-fp32 GEMM.
// logits = x @ W^T + b with x=x1+x2+x3, W=w1+w2+w3 (bf16, exact residuals);
// 6 MFMA terms (>=2^-18) accumulated fp32 => splitting error ~2^-25 rel,
// better than fp32 reorder error that already passed. Then softmax/top-2 fused.
// Outputs (fp32 concat): weights [N,2], indices [N,2] (as float), mask [N,64], probs [N,64]

typedef __attribute__((ext_vector_type(8))) short short8;   // 8 bf16 = 4 VGPR
typedef __attribute__((ext_vector_type(4))) float f32x4;

constexpr int D  = 2048;
constexpr int E  = 64;
constexpr int N  = 16384;
constexpr int BT = 32;     // tokens per block
constexpr int BK = 64;     // k per chunk (2 MFMA k-steps)

__device__ inline unsigned short f2bf(float f) {            // RNE fp32->bf16
    unsigned int u = __float_as_uint(f);
    return (unsigned short)((u + 0x7fffu + ((u >> 16) & 1u)) >> 16);
}
__device__ inline float bf2f(unsigned short h) {
    return __uint_as_float(((unsigned int)h) << 16);
}

// ---- W pre-split: W fp32 [64][2048] -> w1,w2,w3 bf16 [64][2048] in d_ws ----
__global__ __launch_bounds__(256) void wsplit_kernel(
    const float* __restrict__ W, unsigned short* __restrict__ w1,
    unsigned short* __restrict__ w2, unsigned short* __restrict__ w3)
{
    const int i = blockIdx.x * 256 + threadIdx.x;   // one float4 per thread
    float4 v = reinterpret_cast<const float4*>(W)[i];
    float f[4] = {v.x, v.y, v.z, v.w};
    unsigned short h1[4], h2[4], h3[4];
    #pragma unroll
    for (int j = 0; j < 4; ++j) {
        h1[j] = f2bf(f[j]);  float r  = f[j] - bf2f(h1[j]);
        h2[j] = f2bf(r);     float r2 = r    - bf2f(h2[j]);
        h3[j] = f2bf(r2);
    }
    uint2 u1 = {(unsigned)h1[0] | ((unsigned)h1[1] << 16), (unsigned)h1[2] | ((unsigned)h1[3] << 16)};
    uint2 u2 = {(unsigned)h2[0] | ((unsigned)h2[1] << 16), (unsigned)h2[2] | ((unsigned)h2[3] << 16)};
    uint2 u3 = {(unsigned)h3[0] | ((unsigned)h3[1] << 16), (unsigned)h3[2] | ((unsigned)h3[3] << 16)};
    reinterpret_cast<uint2*>(w1)[i] = u1;
    reinterpret_cast<uint2*>(w2)[i] = u2;
    reinterpret_cast<uint2*>(w3)[i] = u3;
}

// split a float4 into 3 bf16 quads and store at off, off+4096, off+8192
__device__ inline void split_store(unsigned char* lds, int off, float4 v) {
    float f[4] = {v.x, v.y, v.z, v.w};
    unsigned short a[4], b[4], c[4];
    #pragma unroll
    for (int j = 0; j < 4; ++j) {
        a[j] = f2bf(f[j]);  float r  = f[j] - bf2f(a[j]);
        b[j] = f2bf(r);     float r2 = r    - bf2f(b[j]);
        c[j] = f2bf(r2);
    }
    uint2 ua = {(unsigned)a[0] | ((unsigned)a[1] << 16), (unsigned)a[2] | ((unsigned)a[3] << 16)};
    uint2 ub = {(unsigned)b[0] | ((unsigned)b[1] << 16), (unsigned)b[2] | ((unsigned)b[3] << 16)};
    uint2 uc = {(unsigned)c[0] | ((unsigned)c[1] << 16), (unsigned)c[2] | ((unsigned)c[3] << 16)};
    *reinterpret_cast<uint2*>(lds + off)        = ua;
    *reinterpret_cast<uint2*>(lds + 4096 + off) = ub;
    *reinterpret_cast<uint2*>(lds + 8192 + off) = uc;
}

#define MFMA(A, B, C) __builtin_amdgcn_mfma_f32_16x16x32_bf16(A, B, C, 0, 0, 0)

__global__ __launch_bounds__(256) void gating_mfma(
    const float* __restrict__ x,
    const unsigned short* __restrict__ w1, const unsigned short* __restrict__ w2,
    const unsigned short* __restrict__ w3,
    const float* __restrict__ bias, float* __restrict__ out)
{
    // LDS: X1,X2,X3 [32 rows][128B] @ 0,4096,8192 ; W1,W2,W3 [64 rows][128B] @ 12288,20480,28672
    __shared__ __align__(16) unsigned char lds[36864];
    __shared__ float s_max[BT], s_rinv[BT];
    __shared__ int   s_i1[BT], s_i2[BT];

    const int tid  = threadIdx.x;
    const int lane = tid & 63;
    const int wv   = tid >> 6;
    const int tokBase = blockIdx.x * BT;

    // ---- staging coords ----
    const int xrow = tid >> 4;              // 0..15 (+16 for unit 1)
    const int xq   = tid & 15;              // fp32-quad within 64-k row
    const int wrow = tid >> 3;              // 0..31 (+32 for unit 1)
    const int wq   = tid & 7;               // 8-bf16 unit within row

    const int xswz  = (xrow & 7) << 4;
    const int xoff0 = xrow * 128        + ((xq * 8) ^ xswz);
    const int xoff1 = (xrow + 16) * 128 + ((xq * 8) ^ xswz);     // (xrow+16)&7 == xrow&7
    const int wswz  = (wrow & 7) << 4;
    const int woff0 = wrow * 128        + ((wq * 16) ^ wswz);
    const int woff1 = (wrow + 32) * 128 + ((wq * 16) ^ wswz);

    const float* gx0 = x + (size_t)(tokBase + xrow) * D      + xq * 4;
    const float* gx1 = x + (size_t)(tokBase + xrow + 16) * D + xq * 4;
    const unsigned short* gw0 = w1 + (size_t)wrow * D + wq * 8;
    const unsigned short* gw1 = w2 + (size_t)wrow * D + wq * 8;
    const unsigned short* gw2 = w3 + (size_t)wrow * D + wq * 8;
    const size_t wstep = (size_t)32 * D;    // +32 rows

    // ---- fragment coords (16x16x32: lane holds row l&15, k = (l>>4)*8 + j) ----
    const int fr = lane & 15, fc = lane >> 4;
    const int tw = (wv & 1) * 16;           // wave token base
    const int eb = (wv >> 1) * 32;          // wave expert base (2 groups of 16)
    const int arow = tw + fr;
    const int aswz = (arow & 7) << 4;
    const int ak0  = arow * 128 + ((fc * 16) ^ aswz);
    const int ak1  = arow * 128 + ((64 + fc * 16) ^ aswz);
    const int br0  = eb + fr;
    const int br1  = eb + 16 + fr;
    const int b0swz = (br0 & 7) << 4, b1swz = (br1 & 7) << 4;
    const int b0k0 = br0 * 128 + ((fc * 16) ^ b0swz) + 12288;
    const int b0k1 = br0 * 128 + ((64 + fc * 16) ^ b0swz) + 12288;
    const int b1k0 = br1 * 128 + ((fc * 16) ^ b1swz) + 12288;
    const int b1k1 = br1 * 128 + ((64 + fc * 16) ^ b1swz) + 12288;

    // ---- prefetch chunk 0 ----
    float4 px0 = *reinterpret_cast<const float4*>(gx0);
    float4 px1 = *reinterpret_cast<const float4*>(gx1);
    int4 pw00 = *reinterpret_cast<const int4*>(gw0);
    int4 pw01 = *reinterpret_cast<const int4*>(gw0 + wstep);
    int4 pw10 = *reinterpret_cast<const int4*>(gw1);
    int4 pw11 = *reinterpret_cast<const int4*>(gw1 + wstep);
    int4 pw20 = *reinterpret_cast<const int4*>(gw2);
    int4 pw21 = *reinterpret_cast<const int4*>(gw2 + wstep);

    f32x4 acc0 = {0.f, 0.f, 0.f, 0.f};
    f32x4 acc1 = {0.f, 0.f, 0.f, 0.f};

    for (int kb = 0; kb < D; kb += BK) {
        // stage prefetched chunk into LDS
        split_store(lds, xoff0, px0);
        split_store(lds, xoff1, px1);
        *reinterpret_cast<int4*>(lds + 12288 + woff0) = pw00;
        *reinterpret_cast<int4*>(lds + 12288 + woff1) = pw01;
        *reinterpret_cast<int4*>(lds + 20480 + woff0) = pw10;
        *reinterpret_cast<int4*>(lds + 20480 + woff1) = pw11;
        *reinterpret_cast<int4*>(lds + 28672 + woff0) = pw20;
        *reinterpret_cast<int4*>(lds + 28672 + woff1) = pw21;
        __syncthreads();

        if (kb + BK < D) {      // issue next chunk's loads; land during MFMA
            const int o = kb + BK;
            px0  = *reinterpret_cast<const float4*>(gx0 + o);
            px1  = *reinterpret_cast<const float4*>(gx1 + o);
            pw00 = *reinterpret_cast<const int4*>(gw0 + o);
            pw01 = *reinterpret_cast<const int4*>(gw0 + wstep + o);
            pw10 = *reinterpret_cast<const int4*>(gw1 + o);
            pw11 = *reinterpret_cast<const int4*>(gw1 + wstep + o);
            pw20 = *reinterpret_cast<const int4*>(gw2 + o);
            pw21 = *reinterpret_cast<const int4*>(gw2 + wstep + o);
        }

        #pragma unroll
        for (int ks = 0; ks < 2; ++ks) {
            const int ao = ks ? ak1 : ak0;
            const int bo0 = ks ? b0k1 : b0k0;
            const int bo1 = ks ? b1k1 : b1k0;
            short8 a1 = *reinterpret_cast<const short8*>(lds + ao);
            short8 a2 = *reinterpret_cast<const short8*>(lds + 4096 + ao);
            short8 a3 = *reinterpret_cast<const short8*>(lds + 8192 + ao);
            short8 p10 = *reinterpret_cast<const short8*>(lds + bo0);          // W1 g0
            short8 p20 = *reinterpret_cast<const short8*>(lds + 8192 + bo0);   // W2 g0
            short8 p30 = *reinterpret_cast<const short8*>(lds + 16384 + bo0);  // W3 g0
            short8 p11 = *reinterpret_cast<const short8*>(lds + bo1);
            short8 p21 = *reinterpret_cast<const short8*>(lds + 8192 + bo1);
            short8 p31 = *reinterpret_cast<const short8*>(lds + 16384 + bo1);
            // 6 significant terms per expert group
            acc0 = MFMA(a1, p10, acc0);
            acc0 = MFMA(a1, p20, acc0);
            acc0 = MFMA(a2, p10, acc0);
            acc0 = MFMA(a1, p30, acc0);
            acc0 = MFMA(a3, p10, acc0);
            acc0 = MFMA(a2, p20, acc0);
            acc1 = MFMA(a1, p11, acc1);
            acc1 = MFMA(a1, p21, acc1);
            acc1 = MFMA(a2, p11, acc1);
            acc1 = MFMA(a1, p31, acc1);
            acc1 = MFMA(a3, p11, acc1);
            acc1 = MFMA(a2, p21, acc1);
        }
        __syncthreads();
    }

    // ---- epilogue: logits -> LDS (reuse X region), softmax/top-2 ----
    float* lg = reinterpret_cast<float*>(lds);      // [32][65]
    const float bv0 = bias[eb + fr];
    const float bv1 = bias[eb + 16 + fr];
    #pragma unroll
    for (int r = 0; r < 4; ++r) {
        const int tok = tw + fc * 4 + r;            // C/D: col=lane&15, row=(lane>>4)*4+r
        lg[tok * 65 + eb + fr]      = acc0[r] + bv0;
        lg[tok * 65 + eb + 16 + fr] = acc1[r] + bv1;
    }
    __syncthreads();

    float* outWt = out;
    float* outIx = out + (size_t)N * 2;
    float* outMk = out + (size_t)N * 4;
    float* outPr = out + (size_t)N * 4 + (size_t)N * E;

    if (tid < BT) {
        const int t = tid;
        float m1 = -3.4e38f, m2 = -3.4e38f;
        int i1 = 0, i2 = 0;
        for (int e = 0; e < E; ++e) {
            const float l = lg[t * 65 + e];
            if (l > m1)      { m2 = m1; i2 = i1; m1 = l; i1 = e; }
            else if (l > m2) { m2 = l;  i2 = e; }
        }
        float ssum = 0.f;
        for (int e = 0; e < E; ++e) ssum += expf(lg[t * 65 + e] - m1);
        const float e2 = expf(m2 - m1);
        const float inv12 = 1.f / (1.f + e2);
        const size_t g = (size_t)(tokBase + t);
        outWt[g * 2 + 0] = inv12;
        outWt[g * 2 + 1] = e2 * inv12;
        outIx[g * 2 + 0] = (float)i1;
        outIx[g * 2 + 1] = (float)i2;
        s_max[t]  = m1;
        s_rinv[t] = 1.f / ssum;
        s_i1[t]   = i1;
        s_i2[t]   = i2;
    }
    __syncthreads();

    for (int f = tid; f < BT * E; f += 256) {
        const int t = f >> 6;
        const int e = f & 63;
        const float p = expf(lg[t * 65 + e] - s_max[t]) * s_rinv[t];
        const size_t g = (size_t)(tokBase + t) * E + e;
        outPr[g] = p;
        outMk[g] = (e == s_i1[t] || e == s_i2[t]) ? 1.0f : 0.0f;
    }
}

extern "C" void kernel_launch(void* const* d_in, const int* in_sizes, int n_in,
                              void* d_out, int out_size, void* d_ws, size_t ws_size,
                              hipStream_t stream) {
    const float* x = (const float*)d_in[0];
    const float* W = (const float*)d_in[1];
    const float* b = (const float*)d_in[2];
    float* out = (float*)d_out;

    unsigned short* w1 = (unsigned short*)d_ws;          // [64][2048] bf16 each
    unsigned short* w2 = w1 + (size_t)E * D;
    unsigned short* w3 = w2 + (size_t)E * D;

    wsplit_kernel<<<dim3(E * D / 4 / 256), dim3(256), 0, stream>>>(W, w1, w2, w3);
    gating_mfma<<<dim3(N / BT), dim3(256), 0, stream>>>(x, w1, w2, w3, b, out);
}